// Round 9
// baseline (136.229 us; speedup 1.0000x reference)
//
#include <hip/hip_runtime.h>

static constexpr int NN  = 100000;
static constexpr int NE  = 2400000;
static constexpr int BSH = 7;            // fine bucket shift (128 nodes)
static constexpr int BSZ = 128;          // nodes per fine bucket
static constexpr int NB  = (NN + BSZ - 1) / BSZ;   // 782 fine buckets
static constexpr int NBP = 1024;         // padded fine-bucket count
static constexpr int MSH  = 9;           // mid bucket shift (512 nodes)
static constexpr unsigned MMSK = 511;
static constexpr int MBN  = (NN + 511) / 512;      // 196 mid buckets
static constexpr int CAPM = 13184;       // per-mid capacity (mean 12245 + 8 sigma)
static constexpr int NPB = 768;          // partition blocks
static constexpr int SEG = NE / NPB;     // 3125 edges per partition block
static constexpr int CAP = 4224;         // fine staging capacity (mean 3070 + 20 sigma)
static_assert(NPB * SEG == NE, "exact segmentation");
static_assert(NB <= NBP, "bucket padding");
static_assert(MBN <= 256, "sbkt uint8");
static_assert(NN % 16 == 0, "16-lane-per-node kernels assume NN % 16 == 0");

// init mid cursors + zero fine counts
__global__ __launch_bounds__(256) void kz(unsigned* __restrict__ cursorA,
                                          unsigned* __restrict__ hcnt) {
    int i = blockIdx.x * 256 + threadIdx.x;
    if (i < MBN) cursorA[i] = (unsigned)i * CAPM;
    if (i < NBP) hcnt[i] = 0;
}

// pass 1: fine hist (for rowptr) + LDS counting-sort into 196 mid buckets +
// atomic space reservation + COALESCED drain (run length ~16 = 64B)
__global__ __launch_bounds__(256) void kpartA(const int* __restrict__ src,
                                              const int* __restrict__ dst,
                                              unsigned* __restrict__ cursorA,
                                              unsigned* __restrict__ hcnt,
                                              unsigned* __restrict__ csr) {
    __shared__ unsigned scode[SEG];
    __shared__ unsigned char sbkt[SEG];
    __shared__ unsigned fh[NBP];
    __shared__ unsigned hist[MBN], gb[MBN];
    __shared__ unsigned ex[MBN + 1];
    int b = blockIdx.x, t = threadIdx.x;
    for (int k = t; k < NBP; k += 256) fh[k] = 0;
    __syncthreads();
    int off = b * SEG;
    for (int j = t; j < SEG; j += 256)
        atomicAdd(&fh[(unsigned)dst[off + j] >> BSH], 1u);
    __syncthreads();
    if (t < MBN) {
        unsigned s = fh[4 * t] + fh[4 * t + 1] + fh[4 * t + 2] + fh[4 * t + 3];
        hist[t] = s;
        gb[t] = s ? atomicAdd(&cursorA[t], s) : 0u;   // reserve global space
    }
    for (int k = t; k < NBP; k += 256)
        if (fh[k]) atomicAdd(&hcnt[k], fh[k]);        // deterministic int sums
    __syncthreads();
    if (t == 0) {
        unsigned run = 0;
        for (int k = 0; k < MBN; ++k) { ex[k] = run; run += hist[k]; }
        ex[MBN] = run;
    }
    __syncthreads();
    if (t < MBN) hist[t] = ex[t];    // reuse as LDS scatter cursor
    __syncthreads();
    for (int j = t; j < SEG; j += 256) {
        unsigned d = (unsigned)dst[off + j], s = (unsigned)src[off + j];
        unsigned bk = d >> MSH;
        unsigned p = atomicAdd(&hist[bk], 1u);
        scode[p] = (s << MSH) | (d & MMSK);
        sbkt[p] = (unsigned char)bk;
    }
    __syncthreads();
    // drain: consecutive threads write consecutive slots of ~16-long runs
    for (int i = t; i < SEG; i += 256) {
        unsigned bk = sbkt[i];
        unsigned dest = gb[bk] + ((unsigned)i - ex[bk]);
        if (dest < (bk + 1u) * CAPM) csr[dest] = scode[i];   // overflow guard
    }
}

// exclusive scan of 1024 fine counts -> basep
__global__ __launch_bounds__(1024) void kbs(const unsigned* __restrict__ hcnt,
                                            unsigned* __restrict__ basep) {
    __shared__ unsigned a[1024], b2[1024];
    int t = threadIdx.x;
    unsigned v = hcnt[t];
    a[t] = v;
    __syncthreads();
    unsigned* cur = a; unsigned* nxt = b2;
    for (int off = 1; off < 1024; off <<= 1) {
        unsigned x = cur[t];
        if (t >= off) x += cur[t - off];
        nxt[t] = x;
        __syncthreads();
        unsigned* tmp = cur; cur = nxt; nxt = tmp;
    }
    basep[t] = cur[t] - v;
    if (t == 1023) basep[1024] = cur[t];
}

// pass 2: fine bucket f filters its mid region (L2/L3-hot), LDS counting-sort
// by local node, coalesced csr2 write; emits rowptr, dis, y1
__global__ __launch_bounds__(256) void kcsrB(const unsigned* __restrict__ csr,
                                             const unsigned* __restrict__ cursorA,
                                             const unsigned* __restrict__ basep,
                                             const float* __restrict__ x,
                                             unsigned* __restrict__ csr2,
                                             unsigned* __restrict__ rowptr,
                                             float* __restrict__ dis,
                                             float* __restrict__ y1) {
    __shared__ unsigned codes[CAP];
    __shared__ unsigned sorted[CAP];
    __shared__ int cnt[BSZ];
    __shared__ int sa[BSZ], sb2[BSZ];
    __shared__ unsigned cur[BSZ];
    __shared__ unsigned top;
    int f = blockIdx.x, t = threadIdx.x;
    unsigned m = (unsigned)f >> 2, fl = (unsigned)f & 3;
    unsigned sbase = m * (unsigned)CAPM;
    unsigned nM = cursorA[m] - sbase;
    if (nM > CAPM) nM = CAPM;
    if (t < BSZ) cnt[t] = 0;
    if (t == 0) top = 0;
    __syncthreads();
    for (unsigned j = t; j < nM; j += 256) {
        unsigned c = csr[sbase + j];
        unsigned loc = c & MMSK;
        if ((loc >> BSH) == fl) {
            atomicAdd(&cnt[loc & (BSZ - 1)], 1);
            unsigned p = atomicAdd(&top, 1u);
            if (p < CAP) codes[p] = c;
        }
    }
    __syncthreads();
    unsigned n = top; if (n > CAP) n = CAP;
    if (t < BSZ) sa[t] = cnt[t];
    __syncthreads();
    int* cp = sa; int* xs = sb2;
    for (int o = 1; o < BSZ; o <<= 1) {
        if (t < BSZ) { int v = cp[t]; if (t >= o) v += cp[t - o]; xs[t] = v; }
        __syncthreads();
        int* tmp = cp; cp = xs; xs = tmp;
    }
    unsigned s0 = basep[f];
    int node = f * BSZ + t;
    if (t < BSZ) {
        int excl = cp[t] - cnt[t];
        cur[t] = (unsigned)excl;
        if (node < NN) {
            rowptr[node] = s0 + (unsigned)excl;
            float d = rsqrtf((float)(cnt[t] + 1));
            dis[node] = d;
            y1[node] = d * x[node];
        }
    }
    if (f == 0 && t == 0) rowptr[NN] = NE;
    __syncthreads();
    for (unsigned j = t; j < n; j += 256) {
        unsigned cc = codes[j];
        unsigned pos = atomicAdd(&cur[cc & (BSZ - 1)], 1u);
        sorted[pos] = cc >> MSH;       // src node id, grouped by dst node
    }
    __syncthreads();
    for (unsigned j = t; j < n; j += 256) csr2[s0 + j] = sorted[j];
}

// ---- aggregation phase (unchanged from round 5/6/8) ----

__global__ __launch_bounds__(256) void kagg1lin(const unsigned* __restrict__ srcs,
                                                const unsigned* __restrict__ rowptr,
                                                const float* __restrict__ y1,
                                                const float* __restrict__ dis,
                                                const float* __restrict__ W1,
                                                const float* __restrict__ b1,
                                                const float* __restrict__ W2,
                                                float* __restrict__ y2) {
    __shared__ float sW1[32], sb1[32], sW2[512];
    int t = threadIdx.x;
    if (t < 32) { sW1[t] = W1[t]; sb1[t] = b1[t]; }
    for (int i = t; i < 512; i += 256) sW2[i] = W2[i];
    __syncthreads();
    int node = blockIdx.x * 16 + (t >> 4);
    int g = t & 15;
    unsigned r0 = rowptr[node], r1 = rowptr[node + 1];
    float s0 = 0.f, s1 = 0.f;
    unsigned j = r0 + g;
    for (; j + 16 < r1; j += 32) {
        unsigned i0 = srcs[j], i1 = srcs[j + 16];
        float v0 = y1[i0], v1 = y1[i1];
        s0 += v0; s1 += v1;
    }
    if (j < r1) s0 += y1[srcs[j]];
    float sum = s0 + s1;
    sum += __shfl_xor(sum, 1, 16);
    sum += __shfl_xor(sum, 2, 16);
    sum += __shfl_xor(sum, 4, 16);
    sum += __shfl_xor(sum, 8, 16);          // all 16 lanes hold the total
    float d = dis[node];
    float a = d * (sum + y1[node]);
    float acc = 0.f;
#pragma unroll
    for (int f = 0; f < 32; ++f) {
        float h = fmaxf(a * sW1[f] + sb1[f], 0.f);
        acc += h * sW2[f * 16 + g];
    }
    y2[(size_t)node * 16 + g] = d * acc;
}

__global__ __launch_bounds__(256) void kagg16g(const unsigned* __restrict__ srcs,
                                               const unsigned* __restrict__ rowptr,
                                               const float* __restrict__ y2,
                                               const float* __restrict__ dis,
                                               const float* __restrict__ b2,
                                               const float* __restrict__ W3,
                                               float* __restrict__ y3) {
    int t = threadIdx.x;
    int node = blockIdx.x * 16 + (t >> 4);
    int g = t & 15;
    unsigned r0 = rowptr[node], r1 = rowptr[node + 1];
    const float* yg = y2 + g;
    float s0 = 0.f, s1 = 0.f, s2 = 0.f, s3 = 0.f;
    unsigned j = r0;
    for (; j + 8 <= r1; j += 8) {
        unsigned i0 = srcs[j + 0], i1 = srcs[j + 1], i2 = srcs[j + 2], i3 = srcs[j + 3];
        unsigned i4 = srcs[j + 4], i5 = srcs[j + 5], i6 = srcs[j + 6], i7 = srcs[j + 7];
        float v0 = yg[(size_t)i0 * 16], v1 = yg[(size_t)i1 * 16];
        float v2 = yg[(size_t)i2 * 16], v3 = yg[(size_t)i3 * 16];
        float v4 = yg[(size_t)i4 * 16], v5 = yg[(size_t)i5 * 16];
        float v6 = yg[(size_t)i6 * 16], v7 = yg[(size_t)i7 * 16];
        s0 += v0; s1 += v1; s2 += v2; s3 += v3;
        s0 += v4; s1 += v5; s2 += v6; s3 += v7;
    }
    for (; j + 2 <= r1; j += 2) {
        unsigned i0 = srcs[j], i1 = srcs[j + 1];
        float v0 = yg[(size_t)i0 * 16], v1 = yg[(size_t)i1 * 16];
        s0 += v0; s1 += v1;
    }
    if (j < r1) s2 += yg[(size_t)srcs[j] * 16];
    float sum = (s0 + s1) + (s2 + s3);
    float d = dis[node];
    float a2 = d * (sum + y2[(size_t)node * 16 + g]) + b2[g];
    float hg = fmaxf(a2, 0.f) * W3[g];
    hg += __shfl_xor(hg, 1, 16);
    hg += __shfl_xor(hg, 2, 16);
    hg += __shfl_xor(hg, 4, 16);
    hg += __shfl_xor(hg, 8, 16);
    if (g == 0) y3[node] = d * hg;
}

__global__ __launch_bounds__(256) void kaggsg(const unsigned* __restrict__ srcs,
                                              const unsigned* __restrict__ rowptr,
                                              const float* __restrict__ y,
                                              const float* __restrict__ dis,
                                              float* __restrict__ out,
                                              const float* __restrict__ bias) {
    int t = threadIdx.x;
    int node = blockIdx.x * 16 + (t >> 4);
    int g = t & 15;
    unsigned r0 = rowptr[node], r1 = rowptr[node + 1];
    float s0 = 0.f, s1 = 0.f;
    unsigned j = r0 + g;
    for (; j + 16 < r1; j += 32) {
        unsigned i0 = srcs[j], i1 = srcs[j + 16];
        float v0 = y[i0], v1 = y[i1];
        s0 += v0; s1 += v1;
    }
    if (j < r1) s0 += y[srcs[j]];
    float sum = s0 + s1;
    sum += __shfl_xor(sum, 1, 16);
    sum += __shfl_xor(sum, 2, 16);
    sum += __shfl_xor(sum, 4, 16);
    sum += __shfl_xor(sum, 8, 16);
    if (g == 0) {
        float d = dis[node];
        out[node] = d * (sum + y[node]) + (bias ? bias[0] : 0.f);
    }
}

extern "C" void kernel_launch(void* const* d_in, const int* in_sizes, int n_in,
                              void* d_out, int out_size, void* d_ws, size_t ws_size,
                              hipStream_t stream) {
    const float* x  = (const float*)d_in[0];
    const int*   ei = (const int*)d_in[1];
    const int* src = ei;
    const int* dst = ei + NE;
    const float* W1 = (const float*)d_in[2];
    const float* b1 = (const float*)d_in[3];
    const float* W2 = (const float*)d_in[4];
    const float* b2 = (const float*)d_in[5];
    const float* W3 = (const float*)d_in[6];
    const float* b3 = (const float*)d_in[7];
    float* out = (float*)d_out;

    auto align256 = [](size_t v) { return (v + 255) & ~(size_t)255; };
    char* w = (char*)d_ws;
    auto carve = [&](size_t bytes) { char* p = w; w += align256(bytes); return p; };

    // region A: mid-bucket regions (dead after kcsrB) -> reused as y2
    size_t regA_sz = (size_t)MBN * CAPM * 4;                  // 10.3 MB
    if (regA_sz < (size_t)NN * 16 * 4) regA_sz = (size_t)NN * 16 * 4;
    char* regA = carve(regA_sz);
    unsigned* csr = (unsigned*)regA;
    float*    y2  = (float*)regA;
    unsigned* csr2    = (unsigned*)carve((size_t)NE * 4);     // 9.6 MB
    unsigned* cursorA = (unsigned*)carve((size_t)MBN * 4);
    unsigned* hcnt    = (unsigned*)carve((size_t)NBP * 4);
    unsigned* basep   = (unsigned*)carve((size_t)(NBP + 1) * 4);
    unsigned* rowptr  = (unsigned*)carve((size_t)(NN + 1) * 4);
    float*    dis     = (float*)   carve((size_t)NN * 4);
    float*    y1      = (float*)   carve((size_t)NN * 4);
    float*    y3      = (float*)   carve((size_t)NN * 4);

    dim3 B(256);

    // partition: init -> mid-bucket sort (coalesced drain) -> scan -> fine sort
    kz     <<<4, B, 0, stream>>>(cursorA, hcnt);
    kpartA <<<NPB, B, 0, stream>>>(src, dst, cursorA, hcnt, csr);
    kbs    <<<1, dim3(1024), 0, stream>>>(hcnt, basep);
    kcsrB  <<<NB, B, 0, stream>>>(csr, cursorA, basep, x, csr2, rowptr, dis, y1);

    // layer 1 aggregate + dense 1->32->16 -> y2 = dis*h2pre
    kagg1lin<<<NN / 16, B, 0, stream>>>(csr2, rowptr, y1, dis, W1, b1, W2, y2);

    // layer 2 aggregate (16-wide) fused with layer-3 linear -> y3
    kagg16g <<<NN / 16, B, 0, stream>>>(csr2, rowptr, y2, dis, b2, W3, y3);

    // layer 3 aggregate (scalar) -> out
    kaggsg  <<<NN / 16, B, 0, stream>>>(csr2, rowptr, y3, dis, out, b3);
}

// Round 10
// 134.929 us; speedup vs baseline: 1.0096x; 1.0096x over previous
//
#include <hip/hip_runtime.h>

static constexpr int NN  = 100000;
static constexpr int NE  = 2400000;
static constexpr int BSH = 7;            // fine bucket shift (128 nodes)
static constexpr int BSZ = 128;          // nodes per fine bucket
static constexpr int NB  = (NN + BSZ - 1) / BSZ;   // 782 fine buckets
static constexpr int MSH  = 9;           // mid bucket shift (512 nodes)
static constexpr unsigned MMSK = 511;
static constexpr int MBN  = (NN + 511) / 512;      // 196 mid buckets
static constexpr int CAPM = 13184;       // per-mid capacity (mean 12245 + ~8.5 sigma)
static constexpr int NPB = 1024;         // partition blocks
static constexpr int SEG = 2344;         // edges per partition block (last ragged)
static constexpr int CAP = 4224;         // fine staging capacity (mean 3070 + 20 sigma)
static_assert((size_t)NPB * SEG >= NE, "segments cover edge list");
static_assert(MBN <= 256, "sbkt uint8 + 256-wide scan");
static_assert(NN % 16 == 0, "16-lane-per-node kernels assume NN % 16 == 0");

// init mid cursors + compact csr2 cursor
__global__ __launch_bounds__(256) void kz(unsigned* __restrict__ cursorA,
                                          unsigned* __restrict__ csr2cur) {
    int i = threadIdx.x;
    if (i < MBN) cursorA[i] = (unsigned)i * CAPM;
    if (i == 0) csr2cur[0] = 0;
}

// pass 1: LDS counting-sort into 196 mid buckets + atomic space reservation +
// coalesced drain (run length ~12 = 48B). Parallel block scan, no fine hist.
__global__ __launch_bounds__(256) void kpartA(const int* __restrict__ src,
                                              const int* __restrict__ dst,
                                              unsigned* __restrict__ cursorA,
                                              unsigned* __restrict__ csr) {
    __shared__ unsigned scode[SEG];
    __shared__ unsigned char sbkt[SEG];
    __shared__ unsigned hist[MBN], gb[MBN], ex[MBN];
    __shared__ unsigned sc1[256], sc2[256];
    int b = blockIdx.x, t = threadIdx.x;
    for (int k = t; k < MBN; k += 256) hist[k] = 0;
    __syncthreads();
    int off = b * SEG;
    int n = NE - off; if (n > SEG) n = SEG; if (n < 0) n = 0;
    for (int j = t; j < n; j += 256)
        atomicAdd(&hist[(unsigned)dst[off + j] >> MSH], 1u);
    __syncthreads();
    // parallel exclusive scan over MBN (padded to 256)
    unsigned hv = (t < MBN) ? hist[t] : 0u;
    sc1[t] = hv;
    __syncthreads();
    unsigned* cu = sc1; unsigned* nx = sc2;
    for (int o = 1; o < 256; o <<= 1) {
        unsigned v = cu[t];
        if (t >= o) v += cu[t - o];
        nx[t] = v;
        __syncthreads();
        unsigned* tm = cu; cu = nx; nx = tm;
    }
    if (t < MBN) {
        ex[t] = cu[t] - hv;
        gb[t] = hv ? atomicAdd(&cursorA[t], hv) : 0u;   // reserve global space
    }
    __syncthreads();
    if (t < MBN) hist[t] = ex[t];      // reuse as LDS scatter cursor
    __syncthreads();
    for (int j = t; j < n; j += 256) {
        unsigned d = (unsigned)dst[off + j], s = (unsigned)src[off + j];
        unsigned bk = d >> MSH;
        unsigned p = atomicAdd(&hist[bk], 1u);
        scode[p] = (s << MSH) | (d & MMSK);
        sbkt[p] = (unsigned char)bk;
    }
    __syncthreads();
    // drain: consecutive threads write consecutive slots of ~12-long runs
    for (int i = t; i < n; i += 256) {
        unsigned bk = sbkt[i];
        unsigned dest = gb[bk] + ((unsigned)i - ex[bk]);
        if (dest < (bk + 1u) * CAPM) csr[dest] = scode[i];   // overflow guard
    }
}

// pass 2: fine bucket f filters its mid region (L2/L3-hot), LDS counting-sort
// by local node, reserves compact csr2 space, coalesced csr2 write;
// emits rstart/rcnt, dis, y1
__global__ __launch_bounds__(256) void kcsrB(const unsigned* __restrict__ csr,
                                             const unsigned* __restrict__ cursorA,
                                             unsigned* __restrict__ csr2cur,
                                             const float* __restrict__ x,
                                             unsigned* __restrict__ csr2,
                                             unsigned* __restrict__ rstart,
                                             unsigned* __restrict__ rcnt,
                                             float* __restrict__ dis,
                                             float* __restrict__ y1) {
    __shared__ unsigned codes[CAP];
    __shared__ unsigned sorted[CAP];
    __shared__ int cnt[BSZ];
    __shared__ int sa[BSZ], sb2[BSZ];
    __shared__ unsigned cur[BSZ];
    __shared__ unsigned top, resv;
    int f = blockIdx.x, t = threadIdx.x;
    unsigned m = (unsigned)f >> 2, fl = (unsigned)f & 3;
    unsigned sbase = m * (unsigned)CAPM;
    unsigned nM = cursorA[m] - sbase;
    if (nM > CAPM) nM = CAPM;
    if (t < BSZ) cnt[t] = 0;
    if (t == 0) top = 0;
    __syncthreads();
    for (unsigned j = t; j < nM; j += 256) {
        unsigned c = csr[sbase + j];
        unsigned loc = c & MMSK;
        if ((loc >> BSH) == fl) {
            atomicAdd(&cnt[loc & (BSZ - 1)], 1);
            unsigned p = atomicAdd(&top, 1u);
            if (p < CAP) codes[p] = c;
        }
    }
    __syncthreads();
    unsigned n = top; if (n > CAP) n = CAP;
    if (t == 0) resv = atomicAdd(csr2cur, n);
    if (t < BSZ) sa[t] = cnt[t];
    __syncthreads();
    int* cp = sa; int* xs = sb2;
    for (int o = 1; o < BSZ; o <<= 1) {
        if (t < BSZ) { int v = cp[t]; if (t >= o) v += cp[t - o]; xs[t] = v; }
        __syncthreads();
        int* tmp = cp; cp = xs; xs = tmp;
    }
    unsigned s0 = resv;
    int node = f * BSZ + t;
    if (t < BSZ) {
        int excl = cp[t] - cnt[t];
        cur[t] = (unsigned)excl;
        if (node < NN) {
            rstart[node] = s0 + (unsigned)excl;
            rcnt[node] = (unsigned)cnt[t];
            float d = rsqrtf((float)(cnt[t] + 1));
            dis[node] = d;
            y1[node] = d * x[node];
        }
    }
    __syncthreads();
    for (unsigned j = t; j < n; j += 256) {
        unsigned cc = codes[j];
        unsigned pos = atomicAdd(&cur[cc & (BSZ - 1)], 1u);
        sorted[pos] = cc >> MSH;       // src node id, grouped by dst node
    }
    __syncthreads();
    for (unsigned j = t; j < n; j += 256) csr2[s0 + j] = sorted[j];
}

// ---- aggregation phase (round-5 structure, rstart/rcnt addressing) ----

__global__ __launch_bounds__(256) void kagg1lin(const unsigned* __restrict__ srcs,
                                                const unsigned* __restrict__ rstart,
                                                const unsigned* __restrict__ rcnt,
                                                const float* __restrict__ y1,
                                                const float* __restrict__ dis,
                                                const float* __restrict__ W1,
                                                const float* __restrict__ b1,
                                                const float* __restrict__ W2,
                                                float* __restrict__ y2) {
    __shared__ float sW1[32], sb1[32], sW2[512];
    int t = threadIdx.x;
    if (t < 32) { sW1[t] = W1[t]; sb1[t] = b1[t]; }
    for (int i = t; i < 512; i += 256) sW2[i] = W2[i];
    __syncthreads();
    int node = blockIdx.x * 16 + (t >> 4);
    int g = t & 15;
    unsigned r0 = rstart[node], r1 = r0 + rcnt[node];
    float s0 = 0.f, s1 = 0.f;
    unsigned j = r0 + g;
    for (; j + 16 < r1; j += 32) {
        unsigned i0 = srcs[j], i1 = srcs[j + 16];
        float v0 = y1[i0], v1 = y1[i1];
        s0 += v0; s1 += v1;
    }
    if (j < r1) s0 += y1[srcs[j]];
    float sum = s0 + s1;
    sum += __shfl_xor(sum, 1, 16);
    sum += __shfl_xor(sum, 2, 16);
    sum += __shfl_xor(sum, 4, 16);
    sum += __shfl_xor(sum, 8, 16);          // all 16 lanes hold the total
    float d = dis[node];
    float a = d * (sum + y1[node]);
    float acc = 0.f;
#pragma unroll
    for (int f = 0; f < 32; ++f) {
        float h = fmaxf(a * sW1[f] + sb1[f], 0.f);
        acc += h * sW2[f * 16 + g];
    }
    y2[(size_t)node * 16 + g] = d * acc;
}

__global__ __launch_bounds__(256) void kagg16g(const unsigned* __restrict__ srcs,
                                               const unsigned* __restrict__ rstart,
                                               const unsigned* __restrict__ rcnt,
                                               const float* __restrict__ y2,
                                               const float* __restrict__ dis,
                                               const float* __restrict__ b2,
                                               const float* __restrict__ W3,
                                               float* __restrict__ y3) {
    int t = threadIdx.x;
    int node = blockIdx.x * 16 + (t >> 4);
    int g = t & 15;
    unsigned r0 = rstart[node], r1 = r0 + rcnt[node];
    const float* yg = y2 + g;
    float s0 = 0.f, s1 = 0.f, s2 = 0.f, s3 = 0.f;
    unsigned j = r0;
    for (; j + 8 <= r1; j += 8) {
        unsigned i0 = srcs[j + 0], i1 = srcs[j + 1], i2 = srcs[j + 2], i3 = srcs[j + 3];
        unsigned i4 = srcs[j + 4], i5 = srcs[j + 5], i6 = srcs[j + 6], i7 = srcs[j + 7];
        float v0 = yg[(size_t)i0 * 16], v1 = yg[(size_t)i1 * 16];
        float v2 = yg[(size_t)i2 * 16], v3 = yg[(size_t)i3 * 16];
        float v4 = yg[(size_t)i4 * 16], v5 = yg[(size_t)i5 * 16];
        float v6 = yg[(size_t)i6 * 16], v7 = yg[(size_t)i7 * 16];
        s0 += v0; s1 += v1; s2 += v2; s3 += v3;
        s0 += v4; s1 += v5; s2 += v6; s3 += v7;
    }
    for (; j + 2 <= r1; j += 2) {
        unsigned i0 = srcs[j], i1 = srcs[j + 1];
        float v0 = yg[(size_t)i0 * 16], v1 = yg[(size_t)i1 * 16];
        s0 += v0; s1 += v1;
    }
    if (j < r1) s2 += yg[(size_t)srcs[j] * 16];
    float sum = (s0 + s1) + (s2 + s3);
    float d = dis[node];
    float a2 = d * (sum + y2[(size_t)node * 16 + g]) + b2[g];
    float hg = fmaxf(a2, 0.f) * W3[g];
    hg += __shfl_xor(hg, 1, 16);
    hg += __shfl_xor(hg, 2, 16);
    hg += __shfl_xor(hg, 4, 16);
    hg += __shfl_xor(hg, 8, 16);
    if (g == 0) y3[node] = d * hg;
}

__global__ __launch_bounds__(256) void kaggsg(const unsigned* __restrict__ srcs,
                                              const unsigned* __restrict__ rstart,
                                              const unsigned* __restrict__ rcnt,
                                              const float* __restrict__ y,
                                              const float* __restrict__ dis,
                                              float* __restrict__ out,
                                              const float* __restrict__ bias) {
    int t = threadIdx.x;
    int node = blockIdx.x * 16 + (t >> 4);
    int g = t & 15;
    unsigned r0 = rstart[node], r1 = r0 + rcnt[node];
    float s0 = 0.f, s1 = 0.f;
    unsigned j = r0 + g;
    for (; j + 16 < r1; j += 32) {
        unsigned i0 = srcs[j], i1 = srcs[j + 16];
        float v0 = y[i0], v1 = y[i1];
        s0 += v0; s1 += v1;
    }
    if (j < r1) s0 += y[srcs[j]];
    float sum = s0 + s1;
    sum += __shfl_xor(sum, 1, 16);
    sum += __shfl_xor(sum, 2, 16);
    sum += __shfl_xor(sum, 4, 16);
    sum += __shfl_xor(sum, 8, 16);
    if (g == 0) {
        float d = dis[node];
        out[node] = d * (sum + y[node]) + (bias ? bias[0] : 0.f);
    }
}

extern "C" void kernel_launch(void* const* d_in, const int* in_sizes, int n_in,
                              void* d_out, int out_size, void* d_ws, size_t ws_size,
                              hipStream_t stream) {
    const float* x  = (const float*)d_in[0];
    const int*   ei = (const int*)d_in[1];
    const int* src = ei;
    const int* dst = ei + NE;
    const float* W1 = (const float*)d_in[2];
    const float* b1 = (const float*)d_in[3];
    const float* W2 = (const float*)d_in[4];
    const float* b2 = (const float*)d_in[5];
    const float* W3 = (const float*)d_in[6];
    const float* b3 = (const float*)d_in[7];
    float* out = (float*)d_out;

    auto align256 = [](size_t v) { return (v + 255) & ~(size_t)255; };
    char* w = (char*)d_ws;
    auto carve = [&](size_t bytes) { char* p = w; w += align256(bytes); return p; };

    // region A: mid-bucket regions (dead after kcsrB) -> reused as y2
    size_t regA_sz = (size_t)MBN * CAPM * 4;                  // 10.3 MB
    if (regA_sz < (size_t)NN * 16 * 4) regA_sz = (size_t)NN * 16 * 4;
    char* regA = carve(regA_sz);
    unsigned* csr = (unsigned*)regA;
    float*    y2  = (float*)regA;
    unsigned* csr2    = (unsigned*)carve((size_t)NE * 4);     // 9.6 MB
    unsigned* cursorA = (unsigned*)carve((size_t)MBN * 4);
    unsigned* csr2cur = (unsigned*)carve(256);
    unsigned* rstart  = (unsigned*)carve((size_t)NN * 4);
    unsigned* rcnt    = (unsigned*)carve((size_t)NN * 4);
    float*    dis     = (float*)   carve((size_t)NN * 4);
    float*    y1      = (float*)   carve((size_t)NN * 4);
    float*    y3      = (float*)   carve((size_t)NN * 4);

    dim3 B(256);

    // partition: init -> mid-bucket sort (coalesced drain) -> fine sort+reserve
    kz     <<<1, B, 0, stream>>>(cursorA, csr2cur);
    kpartA <<<NPB, B, 0, stream>>>(src, dst, cursorA, csr);
    kcsrB  <<<NB, B, 0, stream>>>(csr, cursorA, csr2cur, x, csr2, rstart, rcnt, dis, y1);

    // layer 1 aggregate + dense 1->32->16 -> y2 = dis*h2pre
    kagg1lin<<<NN / 16, B, 0, stream>>>(csr2, rstart, rcnt, y1, dis, W1, b1, W2, y2);

    // layer 2 aggregate (16-wide) fused with layer-3 linear -> y3
    kagg16g <<<NN / 16, B, 0, stream>>>(csr2, rstart, rcnt, y2, dis, b2, W3, y3);

    // layer 3 aggregate (scalar) -> out
    kaggsg  <<<NN / 16, B, 0, stream>>>(csr2, rstart, rcnt, y3, dis, out, b3);
}